// Round 6
// baseline (321.139 us; speedup 1.0000x reference)
//
#include <hip/hip_runtime.h>

// Problem constants
#define BB 8
#define TT 1024
#define NH 8
#define HD 64
#define QT 128   // q rows per attention block

typedef unsigned short u16;
typedef __attribute__((ext_vector_type(8))) short bf16x8;
typedef __attribute__((ext_vector_type(16))) float f32x16;

__device__ __forceinline__ float bf2f(u16 s) {
    union { unsigned u; float f; } v; v.u = ((unsigned)s) << 16; return v.f;
}
__device__ __forceinline__ u16 f2bf(float f) {
    union { float f; unsigned u; } v; v.f = f;
    unsigned r = (v.u + 0x7FFFu + ((v.u >> 16) & 1u)) >> 16;
    return (u16)r;
}

#define MFMA(a, b, c) __builtin_amdgcn_mfma_f32_32x32x16_bf16((a), (b), (c), 0, 0, 0)

// ---------------------------------------------------------------------------
// Flat fp32 -> bf16 for x (4,194,304 elems) and rel_emb (65,600 elems).
// ---------------------------------------------------------------------------
#define NX4 1048576   // x float4 chunks
#define NR4 16400     // rel float4 chunks
__global__ void cvt_misc(const float* __restrict__ x, const float* __restrict__ rel,
                         u16* __restrict__ xb, u16* __restrict__ relb)
{
    size_t i = (size_t)blockIdx.x * 256 + threadIdx.x;
    const float* src; u16* dst;
    if (i < NX4) { src = x; dst = xb; }
    else {
        i -= NX4;
        if (i >= NR4) return;
        src = rel; dst = relb;
    }
    float4 f = *(const float4*)(src + i * 4);
    ushort4 o;
    o.x = f2bf(f.x); o.y = f2bf(f.y); o.z = f2bf(f.z); o.w = f2bf(f.w);
    *(ushort4*)(dst + i * 4) = o;
}

// ---------------------------------------------------------------------------
// Transpose W [512, N] fp32 -> W^T [N, 512] bf16 (Wq, Wkv, Wout in one grid).
// WqT and WkvT are laid out contiguously (WT_all[1536][512]).
// ---------------------------------------------------------------------------
__global__ __launch_bounds__(256) void cvt_wT(
    const float* __restrict__ Wq, const float* __restrict__ Wkv,
    const float* __restrict__ Wout,
    u16* __restrict__ WqT, u16* __restrict__ WkvT, u16* __restrict__ WoutT)
{
    __shared__ float tile[64][65];
    int bid = blockIdx.x;
    const float* W; u16* Wt; int N, kt, ct;
    if (bid < 64)       { W = Wq;   Wt = WqT;   N = 512;  kt = (bid >> 3) * 64; ct = (bid & 7) * 64; }
    else if (bid < 192) { bid -= 64;  W = Wkv;  Wt = WkvT; N = 1024; kt = (bid >> 4) * 64; ct = (bid & 15) * 64; }
    else                { bid -= 192; W = Wout; Wt = WoutT; N = 512;  kt = (bid >> 3) * 64; ct = (bid & 7) * 64; }

    const int tid = threadIdx.x;
#pragma unroll
    for (int i = 0; i < 16; i++) {
        int e = tid + i * 256;
        int r = e >> 6, c = e & 63;
        tile[r][c] = W[(size_t)(kt + r) * N + ct + c];
    }
    __syncthreads();
#pragma unroll
    for (int i = 0; i < 16; i++) {
        int e = tid + i * 256;
        int rr = e >> 6, cc = e & 63;   // output row = original col
        Wt[(size_t)(ct + rr) * 512 + kt + cc] = f2bf(tile[cc][rr]);
    }
}

// ---------------------------------------------------------------------------
// Fused qkv projection (bf16 MFMA, zero LDS): C = x[8192,512] @ Wqkv + b.
// B given transposed: WT_all[1536][512]. Wave = 32 rows x 64 cols; block =
// 4 waves stacked along M so all waves share B-frag addresses (L1-hot).
// Grid (64, 24): by*64 = output col. c<512: q scaled 0.125 -> [b,h,t,d];
// 512..1024: k -> [b,h,t,d]; 1024..1536: v TRANSPOSED -> [b,h,d,t].
// ---------------------------------------------------------------------------
__global__ __launch_bounds__(256) void gemm_qkv(
    const u16* __restrict__ A, const u16* __restrict__ Bt,
    const float* __restrict__ bq, const float* __restrict__ bkv,
    u16* __restrict__ oq, u16* __restrict__ ok, u16* __restrict__ ov)
{
    const int tid = threadIdx.x;
    const int lane = tid & 63, w = tid >> 6;
    const int l31 = lane & 31, lh = lane >> 5;
    const int row0 = blockIdx.x * 128 + 32 * w;
    const int c0 = blockIdx.y * 64;

    const u16* ap  = A  + (size_t)(row0 + l31) * 512 + 8 * lh;
    const u16* bp0 = Bt + (size_t)(c0 + l31) * 512 + 8 * lh;

    f32x16 acc0, acc1;
#pragma unroll
    for (int i = 0; i < 16; i++) { acc0[i] = 0.f; acc1[i] = 0.f; }

#pragma unroll 4
    for (int ks = 0; ks < 32; ks++) {
        bf16x8 a  = *(const bf16x8*)(ap  + 16 * ks);
        bf16x8 b0 = *(const bf16x8*)(bp0 + 16 * ks);
        bf16x8 b1 = *(const bf16x8*)(bp0 + 32 * 512 + 16 * ks);
        acc0 = MFMA(a, b0, acc0);
        acc1 = MFMA(a, b1, acc1);
    }

    const int rbase = 4 * lh;
    const float* bp = (c0 < 512) ? (bq + c0) : (bkv + (c0 - 512));
    const float bv0 = bp[l31];
    const float bv1 = bp[32 + l31];

    if (c0 < 512) {            // q, scaled by softmax 1/sqrt(d)
        const int h = c0 >> 6;
#pragma unroll
        for (int rg = 0; rg < 16; rg++) {
            int gr = row0 + (rg & 3) + 8 * (rg >> 2) + rbase;
            int b = gr >> 10, t = gr & 1023;
            size_t base = (((size_t)b * NH + h) * TT + t) * HD;
            oq[base + l31]      = f2bf((acc0[rg] + bv0) * 0.125f);
            oq[base + 32 + l31] = f2bf((acc1[rg] + bv1) * 0.125f);
        }
    } else if (c0 < 1024) {    // k
        const int h = (c0 - 512) >> 6;
#pragma unroll
        for (int rg = 0; rg < 16; rg++) {
            int gr = row0 + (rg & 3) + 8 * (rg >> 2) + rbase;
            int b = gr >> 10, t = gr & 1023;
            size_t base = (((size_t)b * NH + h) * TT + t) * HD;
            ok[base + l31]      = f2bf(acc0[rg] + bv0);
            ok[base + 32 + l31] = f2bf(acc1[rg] + bv1);
        }
    } else {                   // v, transposed [b,h,d,t]
        const int h = (c0 - 1024) >> 6;
        const int b = row0 >> 10;
        const int t0 = row0 & 1023;
        size_t base0 = (((size_t)b * NH + h) * HD + l31) * TT;
        size_t base1 = (((size_t)b * NH + h) * HD + 32 + l31) * TT;
#pragma unroll
        for (int g = 0; g < 4; g++) {
            int t = t0 + 8 * g + rbase;
            ushort4 p0, p1;
            p0.x = f2bf(acc0[4 * g + 0] + bv0); p0.y = f2bf(acc0[4 * g + 1] + bv0);
            p0.z = f2bf(acc0[4 * g + 2] + bv0); p0.w = f2bf(acc0[4 * g + 3] + bv0);
            p1.x = f2bf(acc1[4 * g + 0] + bv1); p1.y = f2bf(acc1[4 * g + 1] + bv1);
            p1.z = f2bf(acc1[4 * g + 2] + bv1); p1.w = f2bf(acc1[4 * g + 3] + bv1);
            *(ushort4*)&ov[base0 + t] = p0;
            *(ushort4*)&ov[base1 + t] = p1;
        }
    }
}

// ---------------------------------------------------------------------------
// Out projection: out = a[8192,512] @ Wout + bout, fp32 result.
// Wave = 32 rows x 32 cols -> 4096 waves (16/CU). Grid (64, 16).
// ---------------------------------------------------------------------------
__global__ __launch_bounds__(256) void gemm_out(
    const u16* __restrict__ A, const u16* __restrict__ Bt,
    const float* __restrict__ bias, float* __restrict__ of)
{
    const int tid = threadIdx.x;
    const int lane = tid & 63, w = tid >> 6;
    const int l31 = lane & 31, lh = lane >> 5;
    const int row0 = blockIdx.x * 128 + 32 * w;
    const int c0 = blockIdx.y * 32;

    const u16* ap  = A  + (size_t)(row0 + l31) * 512 + 8 * lh;
    const u16* bp0 = Bt + (size_t)(c0 + l31) * 512 + 8 * lh;

    f32x16 acc0;
#pragma unroll
    for (int i = 0; i < 16; i++) acc0[i] = 0.f;

#pragma unroll 4
    for (int ks = 0; ks < 32; ks++) {
        bf16x8 a  = *(const bf16x8*)(ap  + 16 * ks);
        bf16x8 b0 = *(const bf16x8*)(bp0 + 16 * ks);
        acc0 = MFMA(a, b0, acc0);
    }

    const int rbase = 4 * lh;
    const float bv0 = bias[c0 + l31];
#pragma unroll
    for (int rg = 0; rg < 16; rg++) {
        int gr = row0 + (rg & 3) + 8 * (rg >> 2) + rbase;
        of[(size_t)gr * 512 + c0 + l31] = acc0[rg] + bv0;
    }
}

// ---------------------------------------------------------------------------
// MFMA flash attention, rel-pos via skew gather, barrier-free, 2-way K-split.
// Grid: (T/128, B*H*2) — 2D ONLY (blockIdx.z was common to both container-
// killing rounds; removed defensively). by = bh*2 + split.
// Block: 256 = 4 waves; wave w owns q-rows [32w,32w+32).
// Split s handles m-tiles [8s,8s+8), writes UNNORMALIZED bf16 O partials +
// fp32 partial row-sums (no max tracking; scores bounded, exp can't overflow).
// LDS: per-wave 32x104 u16 G/P buffer (26.6 KB) -> 4 blocks/CU at VGPR cap.
// ---------------------------------------------------------------------------
__global__ __launch_bounds__(256) void attn_mfma(
    const u16* __restrict__ q_ws, const u16* __restrict__ k_ws,
    const u16* __restrict__ v_ws, const u16* __restrict__ relb,
    u16* __restrict__ Opart, float* __restrict__ Lpart)
{
    __shared__ __align__(16) u16 GPs[4][32 * 104];   // per-wave G band / P tile

    const int tid  = threadIdx.x;
    const int lane = tid & 63;
    const int w    = tid >> 6;
    const int l31  = lane & 31;
    const int lh   = lane >> 5;
    const int bh   = blockIdx.y >> 1;
    const int sp   = blockIdx.y & 1;
    const int n0   = blockIdx.x * QT;

    // Q A-fragments (rows n0+32w+l31), held in registers for all m-tiles
    bf16x8 a_q[4];
    {
        const u16* qp = q_ws + (((size_t)bh * TT) + n0 + 32 * w + l31) * HD + 8 * lh;
#pragma unroll
        for (int ks = 0; ks < 4; ks++)
            a_q[ks] = *(const bf16x8*)(qp + 16 * ks);
    }

    f32x16 O0, O1;
    float li[16];
#pragma unroll
    for (int i = 0; i < 16; i++) { O0[i] = 0.f; O1[i] = 0.f; li[i] = 0.f; }

    u16* Gw = GPs[w];
    const int rbase = 4 * lh;

    for (int mt = 8 * sp; mt < 8 * sp + 8; mt++) {
        const int m0 = mt * 64;
        const u16* kb = k_ws + ((size_t)bh * TT + m0) * HD;

        // ---- S = Q K^T  (B-frags straight from global: 8 contiguous d)
        f32x16 S0, S1;
#pragma unroll
        for (int i = 0; i < 16; i++) { S0[i] = 0.f; S1[i] = 0.f; }
#pragma unroll
        for (int ks = 0; ks < 4; ks++) {
            const int doff = 16 * ks + 8 * lh;
            bf16x8 b0 = *(const bf16x8*)(kb + (size_t)l31 * HD + doff);
            bf16x8 b1 = *(const bf16x8*)(kb + (size_t)(l31 + 32) * HD + doff);
            S0 = MFMA(a_q[ks], b0, S0);
            S1 = MFMA(a_q[ks], b1, S1);
        }

        // ---- G = Q R^T (3 col-tiles; rel B-frags straight from global)
        const int pb = n0 - m0 + 449 + 32 * w;
#pragma unroll
        for (int gt = 0; gt < 3; gt++) {
            f32x16 g;
#pragma unroll
            for (int i = 0; i < 16; i++) g[i] = 0.f;
            int p = pb + 32 * gt + l31;
            p = p < 0 ? 0 : (p > 1024 ? 1024 : p);
            const u16* rb = relb + (size_t)p * HD;
#pragma unroll
            for (int ks = 0; ks < 4; ks++) {
                bf16x8 br = *(const bf16x8*)(rb + 16 * ks + 8 * lh);
                g = MFMA(a_q[ks], br, g);
            }
            int jp = 32 * gt + l31;
#pragma unroll
            for (int rg = 0; rg < 16; rg++) {
                int r = (rg & 3) + 8 * (rg >> 2) + rbase;
                Gw[r * 104 + jp] = f2bf(g[rg]);
            }
        }

        // ---- skew gather (wave-private; per-wave DS ordering + compiler waits)
#pragma unroll
        for (int rg = 0; rg < 16; rg++) {
            int r = (rg & 3) + 8 * (rg >> 2) + rbase;
            int j0 = r - l31 + 63;
            S0[rg] += bf2f(Gw[r * 104 + j0]);
            S1[rg] += bf2f(Gw[r * 104 + j0 - 32]);
        }

        // ---- streaming softmax: raw exp, per-lane partial row-sums
#pragma unroll
        for (int rg = 0; rg < 16; rg++) {
            float e0 = __expf(S0[rg]);
            float e1 = __expf(S1[rg]);
            S0[rg] = e0; S1[rg] = e1;
            li[rg] += e0 + e1;
        }

        // ---- P -> LDS bf16 (swizzled, wave-private)
#pragma unroll
        for (int rg = 0; rg < 16; rg++) {
            int r = (rg & 3) + 8 * (rg >> 2) + rbase;
            int ca = l31, cb = l31 + 32;
            Gw[r * 104 + (((ca >> 3) ^ (r & 7)) * 8) + (ca & 7)] = f2bf(S0[rg]);
            Gw[r * 104 + (((cb >> 3) ^ (r & 7)) * 8) + (cb & 7)] = f2bf(S1[rg]);
        }

        // ---- O += P V  (V B-frags straight from global: 8 contiguous t)
        const u16* vb = v_ws + (size_t)bh * HD * TT + m0;
#pragma unroll
        for (int ms = 0; ms < 4; ms++) {
            const int mg = 2 * ms + lh;
            bf16x8 a_p = *(const bf16x8*)&Gw[l31 * 104 + ((mg ^ (l31 & 7)) * 8)];
            bf16x8 b0 = *(const bf16x8*)(vb + (size_t)l31 * TT + mg * 8);
            bf16x8 b1 = *(const bf16x8*)(vb + (size_t)(l31 + 32) * TT + mg * 8);
            O0 = MFMA(a_p, b0, O0);
            O1 = MFMA(a_p, b1, O1);
        }
    }

    // ---- reduce li partials across the 32 lanes holding each row
#pragma unroll
    for (int rg = 0; rg < 16; rg++) {
        float rs = li[rg];
        rs += __shfl_xor(rs, 1);
        rs += __shfl_xor(rs, 2);
        rs += __shfl_xor(rs, 4);
        rs += __shfl_xor(rs, 8);
        rs += __shfl_xor(rs, 16);
        li[rg] = rs;
    }

    // ---- write bf16 O partials: Opart[s][bh][n][d]; fp32 Lpart[s][bh][n]
    u16* op = Opart + (((size_t)sp * 64 + bh) * TT + n0 + 32 * w) * HD;
#pragma unroll
    for (int rg = 0; rg < 16; rg++) {
        int r = (rg & 3) + 8 * (rg >> 2) + rbase;
        op[(size_t)r * HD + l31]      = f2bf(O0[rg]);
        op[(size_t)r * HD + 32 + l31] = f2bf(O1[rg]);
    }
    if (l31 == 0) {
        float* lp = Lpart + ((size_t)sp * 64 + bh) * TT + n0 + 32 * w;
#pragma unroll
        for (int rg = 0; rg < 16; rg++) {
            int r = (rg & 3) + 8 * (rg >> 2) + rbase;
            lp[r] = li[rg];
        }
    }
}

// ---------------------------------------------------------------------------
// Combine the 2 attention splits: a = (O0+O1)/(l0+l1) -> bf16 [b,t,h*64+d].
// 256 threads = 16 rows x 16 threads (4 d each). Grid: 65536/16 = 4096.
// ---------------------------------------------------------------------------
__global__ __launch_bounds__(256) void attn_combine(
    const u16* __restrict__ Opart, const float* __restrict__ Lpart,
    u16* __restrict__ a_out)
{
    const int tid = threadIdx.x;
    const int row = blockIdx.x * 16 + (tid >> 4);   // 0..65535 over [bh][t]
    const int dq  = (tid & 15) * 4;
    const int bh = row >> 10, n = row & 1023;

    const size_t OS = (size_t)64 * TT * HD;   // split stride (elems)
    size_t o0 = ((size_t)bh * TT + n) * HD + dq;
    ushort4 p0 = *(const ushort4*)(Opart + o0);
    ushort4 p1 = *(const ushort4*)(Opart + OS + o0);
    float l = Lpart[(size_t)bh * TT + n] + Lpart[(size_t)64 * TT + bh * TT + n];
    float inv = 1.0f / l;

    const int b = bh >> 3, h = bh & 7;
    ushort4 o;
    o.x = f2bf((bf2f(p0.x) + bf2f(p1.x)) * inv);
    o.y = f2bf((bf2f(p0.y) + bf2f(p1.y)) * inv);
    o.z = f2bf((bf2f(p0.z) + bf2f(p1.z)) * inv);
    o.w = f2bf((bf2f(p0.w) + bf2f(p1.w)) * inv);
    *(ushort4*)&a_out[((size_t)b * TT + n) * 512 + h * HD + dq] = o;
}

// ---------------------------------------------------------------------------
// Workspace layout (43 MB total — inside round 3's PROVEN 44 MB envelope).
// Phase overlap: Opart reuses x_bf's region (x dead after qkv GEMM);
// a_wsb reuses q_wsb's region (q dead after attention).
//   [ 0, 8)  q_wsb (phases B-C)  /  a_wsb (phases D-E)
//   [ 8,16)  k_wsb
//   [16,24)  v_wsb
//   [24,32)  x_bf (phases A-B)   /  Opart low half (phase C-D)
//   [32,40)  Opart high half
//   [40,40.5) Lpart     [40.5,41) relb
//   [41,42.5) WT_all    [42.5,43) WoutT
// ---------------------------------------------------------------------------
extern "C" void kernel_launch(void* const* d_in, const int* in_sizes, int n_in,
                              void* d_out, int out_size, void* d_ws, size_t ws_size,
                              hipStream_t stream)
{
    const float* x    = (const float*)d_in[0];
    const float* Wq   = (const float*)d_in[1];
    const float* bq   = (const float*)d_in[2];
    const float* Wkv  = (const float*)d_in[3];
    const float* bkv  = (const float*)d_in[4];
    const float* Wout = (const float*)d_in[5];
    const float* bout = (const float*)d_in[6];
    const float* rel  = (const float*)d_in[7];
    float* out = (float*)d_out;

    char* ws = (char*)d_ws;
    const size_t MB = 1024 * 1024;
    u16*   q_wsb  = (u16*)(ws);                           // 8 MB [b,h,t,d]
    u16*   a_wsb  = (u16*)(ws);                           // reuse (D-E)
    u16*   k_wsb  = (u16*)(ws + 8 * MB);                  // 8 MB [b,h,t,d]
    u16*   v_wsb  = (u16*)(ws + 16 * MB);                 // 8 MB [b,h,d,t]
    u16*   x_bf   = (u16*)(ws + 24 * MB);                 // 8 MB [8192,512]
    u16*   Opart  = (u16*)(ws + 24 * MB);                 // 16 MB reuse (C-D)
    float* Lpart  = (float*)(ws + 40 * MB);               // 512 KB
    u16*   relb   = (u16*)(ws + 40 * MB + 512 * 1024);    // 128 KB
    u16*   WT_all = (u16*)(ws + 41 * MB);                 // 1.5 MB [1536,512]
    u16*   WoutT  = (u16*)(ws + 42 * MB + 512 * 1024);    // 512 KB [512,512]

    // A: dtype conversions
    cvt_misc<<<(NX4 + NR4 + 255) / 256, 256, 0, stream>>>(x, rel, x_bf, relb);
    cvt_wT<<<256, 256, 0, stream>>>(Wq, Wkv, Wout, WT_all, WT_all + 512 * 512, WoutT);

    // B: fused qkv projection (6144 waves = 24/CU)
    gemm_qkv<<<dim3(64, 24), 256, 0, stream>>>(
        x_bf, WT_all, bq, bkv, q_wsb, k_wsb, v_wsb);

    // C: attention, 2-way K-split (1024 blocks = 4/CU)
    attn_mfma<<<dim3(8, 128), 256, 0, stream>>>(
        q_wsb, k_wsb, v_wsb, relb, Opart, Lpart);

    // D: combine splits
    attn_combine<<<4096, 256, 0, stream>>>(Opart, Lpart, a_wsb);

    // E: out projection (4096 waves = 16/CU)
    gemm_out<<<dim3(64, 16), 256, 0, stream>>>(a_wsb, WoutT, bout, out);
}

// Round 8
// 316.884 us; speedup vs baseline: 1.0134x; 1.0134x over previous
//
#include <hip/hip_runtime.h>

// Problem constants
#define BB 8
#define TT 1024
#define NH 8
#define HD 64
#define QT 128   // q rows per attention block

typedef unsigned short u16;
typedef __attribute__((ext_vector_type(8))) short bf16x8;
typedef __attribute__((ext_vector_type(16))) float f32x16;

__device__ __forceinline__ float bf2f(u16 s) {
    union { unsigned u; float f; } v; v.u = ((unsigned)s) << 16; return v.f;
}
__device__ __forceinline__ u16 f2bf(float f) {
    union { float f; unsigned u; } v; v.f = f;
    unsigned r = (v.u + 0x7FFFu + ((v.u >> 16) & 1u)) >> 16;
    return (u16)r;
}

#define MFMA(a, b, c) __builtin_amdgcn_mfma_f32_32x32x16_bf16((a), (b), (c), 0, 0, 0)

// ---------------------------------------------------------------------------
// Flat fp32 -> bf16 for x (4,194,304 elems) and rel_emb (65,600 elems).
// ---------------------------------------------------------------------------
#define NX4 1048576   // x float4 chunks
#define NR4 16400     // rel float4 chunks
__global__ void cvt_misc(const float* __restrict__ x, const float* __restrict__ rel,
                         u16* __restrict__ xb, u16* __restrict__ relb)
{
    size_t i = (size_t)blockIdx.x * 256 + threadIdx.x;
    const float* src; u16* dst;
    if (i < NX4) { src = x; dst = xb; }
    else {
        i -= NX4;
        if (i >= NR4) return;
        src = rel; dst = relb;
    }
    float4 f = *(const float4*)(src + i * 4);
    ushort4 o;
    o.x = f2bf(f.x); o.y = f2bf(f.y); o.z = f2bf(f.z); o.w = f2bf(f.w);
    *(ushort4*)(dst + i * 4) = o;
}

// ---------------------------------------------------------------------------
// Transpose W [512, N] fp32 -> W^T [N, 512] bf16 (Wq, Wkv, Wout in one grid).
// WqT and WkvT are laid out contiguously (WT_all[1536][512]).
// ---------------------------------------------------------------------------
__global__ __launch_bounds__(256) void cvt_wT(
    const float* __restrict__ Wq, const float* __restrict__ Wkv,
    const float* __restrict__ Wout,
    u16* __restrict__ WqT, u16* __restrict__ WkvT, u16* __restrict__ WoutT)
{
    __shared__ float tile[64][65];
    int bid = blockIdx.x;
    const float* W; u16* Wt; int N, kt, ct;
    if (bid < 64)       { W = Wq;   Wt = WqT;   N = 512;  kt = (bid >> 3) * 64; ct = (bid & 7) * 64; }
    else if (bid < 192) { bid -= 64;  W = Wkv;  Wt = WkvT; N = 1024; kt = (bid >> 4) * 64; ct = (bid & 15) * 64; }
    else                { bid -= 192; W = Wout; Wt = WoutT; N = 512;  kt = (bid >> 3) * 64; ct = (bid & 7) * 64; }

    const int tid = threadIdx.x;
#pragma unroll
    for (int i = 0; i < 16; i++) {
        int e = tid + i * 256;
        int r = e >> 6, c = e & 63;
        tile[r][c] = W[(size_t)(kt + r) * N + ct + c];
    }
    __syncthreads();
#pragma unroll
    for (int i = 0; i < 16; i++) {
        int e = tid + i * 256;
        int rr = e >> 6, cc = e & 63;   // output row = original col
        Wt[(size_t)(ct + rr) * 512 + kt + cc] = f2bf(tile[cc][rr]);
    }
}

// ---------------------------------------------------------------------------
// Fused qkv projection (bf16 MFMA, zero LDS): C = x[8192,512] @ Wqkv + b.
// B given transposed: WT_all[1536][512]. Wave = 32 rows x 64 cols; block =
// 4 waves stacked along M so all waves share B-frag addresses (L1-hot).
// Grid (64, 24): by*64 = output col. c<512: q scaled 0.125 -> [b,h,t,d];
// 512..1024: k -> [b,h,t,d]; 1024..1536: v TRANSPOSED -> [b,h,d,t].
// ---------------------------------------------------------------------------
__global__ __launch_bounds__(256) void gemm_qkv(
    const u16* __restrict__ A, const u16* __restrict__ Bt,
    const float* __restrict__ bq, const float* __restrict__ bkv,
    u16* __restrict__ oq, u16* __restrict__ ok, u16* __restrict__ ov)
{
    const int tid = threadIdx.x;
    const int lane = tid & 63, w = tid >> 6;
    const int l31 = lane & 31, lh = lane >> 5;
    const int row0 = blockIdx.x * 128 + 32 * w;
    const int c0 = blockIdx.y * 64;

    const u16* ap  = A  + (size_t)(row0 + l31) * 512 + 8 * lh;
    const u16* bp0 = Bt + (size_t)(c0 + l31) * 512 + 8 * lh;

    f32x16 acc0, acc1;
#pragma unroll
    for (int i = 0; i < 16; i++) { acc0[i] = 0.f; acc1[i] = 0.f; }

#pragma unroll 4
    for (int ks = 0; ks < 32; ks++) {
        bf16x8 a  = *(const bf16x8*)(ap  + 16 * ks);
        bf16x8 b0 = *(const bf16x8*)(bp0 + 16 * ks);
        bf16x8 b1 = *(const bf16x8*)(bp0 + 32 * 512 + 16 * ks);
        acc0 = MFMA(a, b0, acc0);
        acc1 = MFMA(a, b1, acc1);
    }

    const int rbase = 4 * lh;
    const float* bp = (c0 < 512) ? (bq + c0) : (bkv + (c0 - 512));
    const float bv0 = bp[l31];
    const float bv1 = bp[32 + l31];

    if (c0 < 512) {            // q, scaled by softmax 1/sqrt(d)
        const int h = c0 >> 6;
#pragma unroll
        for (int rg = 0; rg < 16; rg++) {
            int gr = row0 + (rg & 3) + 8 * (rg >> 2) + rbase;
            int b = gr >> 10, t = gr & 1023;
            size_t base = (((size_t)b * NH + h) * TT + t) * HD;
            oq[base + l31]      = f2bf((acc0[rg] + bv0) * 0.125f);
            oq[base + 32 + l31] = f2bf((acc1[rg] + bv1) * 0.125f);
        }
    } else if (c0 < 1024) {    // k
        const int h = (c0 - 512) >> 6;
#pragma unroll
        for (int rg = 0; rg < 16; rg++) {
            int gr = row0 + (rg & 3) + 8 * (rg >> 2) + rbase;
            int b = gr >> 10, t = gr & 1023;
            size_t base = (((size_t)b * NH + h) * TT + t) * HD;
            ok[base + l31]      = f2bf(acc0[rg] + bv0);
            ok[base + 32 + l31] = f2bf(acc1[rg] + bv1);
        }
    } else {                   // v, transposed [b,h,d,t]
        const int h = (c0 - 1024) >> 6;
        const int b = row0 >> 10;
        const int t0 = row0 & 1023;
        size_t base0 = (((size_t)b * NH + h) * HD + l31) * TT;
        size_t base1 = (((size_t)b * NH + h) * HD + 32 + l31) * TT;
#pragma unroll
        for (int g = 0; g < 4; g++) {
            int t = t0 + 8 * g + rbase;
            ushort4 p0, p1;
            p0.x = f2bf(acc0[4 * g + 0] + bv0); p0.y = f2bf(acc0[4 * g + 1] + bv0);
            p0.z = f2bf(acc0[4 * g + 2] + bv0); p0.w = f2bf(acc0[4 * g + 3] + bv0);
            p1.x = f2bf(acc1[4 * g + 0] + bv1); p1.y = f2bf(acc1[4 * g + 1] + bv1);
            p1.z = f2bf(acc1[4 * g + 2] + bv1); p1.w = f2bf(acc1[4 * g + 3] + bv1);
            *(ushort4*)&ov[base0 + t] = p0;
            *(ushort4*)&ov[base1 + t] = p1;
        }
    }
}

// ---------------------------------------------------------------------------
// Out projection: out = a[8192,512] @ Wout + bout, fp32 result.
// Wave = 32 rows x 32 cols -> 4096 waves (16/CU). Grid (64, 16).
// ---------------------------------------------------------------------------
__global__ __launch_bounds__(256) void gemm_out(
    const u16* __restrict__ A, const u16* __restrict__ Bt,
    const float* __restrict__ bias, float* __restrict__ of)
{
    const int tid = threadIdx.x;
    const int lane = tid & 63, w = tid >> 6;
    const int l31 = lane & 31, lh = lane >> 5;
    const int row0 = blockIdx.x * 128 + 32 * w;
    const int c0 = blockIdx.y * 32;

    const u16* ap  = A  + (size_t)(row0 + l31) * 512 + 8 * lh;
    const u16* bp0 = Bt + (size_t)(c0 + l31) * 512 + 8 * lh;

    f32x16 acc0;
#pragma unroll
    for (int i = 0; i < 16; i++) acc0[i] = 0.f;

#pragma unroll 4
    for (int ks = 0; ks < 32; ks++) {
        bf16x8 a  = *(const bf16x8*)(ap  + 16 * ks);
        bf16x8 b0 = *(const bf16x8*)(bp0 + 16 * ks);
        acc0 = MFMA(a, b0, acc0);
    }

    const int rbase = 4 * lh;
    const float bv0 = bias[c0 + l31];
#pragma unroll
    for (int rg = 0; rg < 16; rg++) {
        int gr = row0 + (rg & 3) + 8 * (rg >> 2) + rbase;
        of[(size_t)gr * 512 + c0 + l31] = acc0[rg] + bv0;
    }
}

// ---------------------------------------------------------------------------
// MFMA flash attention, rel-pos via skew gather, barrier-free, 2-way K-split.
// Grid: (64, 16) — ONLY change vs the round-6 passing kernel: bx = bh so
// dispatch round-robin (linear%8 = bh%8) clusters all 16 blocks of one bh
// on one XCD; per-XCD K+V working set = 8 bh x 256 KB = 2 MB < 4 MB L2.
// (Round 6's (8,128) mapping gave linear%8 = nt -> every XCD streamed the
// full 16 MB K/V set; FETCH_SIZE showed ~40 MB of L2-miss overfetch.)
// by = nt*2 + sp. Block: 256 = 4 waves; wave w owns q-rows [32w,32w+32).
// Split sp handles m-tiles [8sp,8sp+8), writes UNNORMALIZED bf16 O partials
// + fp32 partial row-sums (no max tracking; scores bounded).
// LDS: per-wave 32x104 u16 G/P buffer (26.6 KB).
// ---------------------------------------------------------------------------
__global__ __launch_bounds__(256) void attn_mfma(
    const u16* __restrict__ q_ws, const u16* __restrict__ k_ws,
    const u16* __restrict__ v_ws, const u16* __restrict__ relb,
    u16* __restrict__ Opart, float* __restrict__ Lpart)
{
    __shared__ __align__(16) u16 GPs[4][32 * 104];   // per-wave G band / P tile

    const int tid  = threadIdx.x;
    const int lane = tid & 63;
    const int w    = tid >> 6;
    const int l31  = lane & 31;
    const int lh   = lane >> 5;
    const int bh   = blockIdx.x;
    const int nt   = blockIdx.y >> 1;
    const int sp   = blockIdx.y & 1;
    const int n0   = nt * QT;

    // Q A-fragments (rows n0+32w+l31), held in registers for all m-tiles
    bf16x8 a_q[4];
    {
        const u16* qp = q_ws + (((size_t)bh * TT) + n0 + 32 * w + l31) * HD + 8 * lh;
#pragma unroll
        for (int ks = 0; ks < 4; ks++)
            a_q[ks] = *(const bf16x8*)(qp + 16 * ks);
    }

    f32x16 O0, O1;
    float li[16];
#pragma unroll
    for (int i = 0; i < 16; i++) { O0[i] = 0.f; O1[i] = 0.f; li[i] = 0.f; }

    u16* Gw = GPs[w];
    const int rbase = 4 * lh;

    for (int mt = 8 * sp; mt < 8 * sp + 8; mt++) {
        const int m0 = mt * 64;
        const u16* kb = k_ws + ((size_t)bh * TT + m0) * HD;

        // ---- S = Q K^T  (B-frags straight from global: 8 contiguous d)
        f32x16 S0, S1;
#pragma unroll
        for (int i = 0; i < 16; i++) { S0[i] = 0.f; S1[i] = 0.f; }
#pragma unroll
        for (int ks = 0; ks < 4; ks++) {
            const int doff = 16 * ks + 8 * lh;
            bf16x8 b0 = *(const bf16x8*)(kb + (size_t)l31 * HD + doff);
            bf16x8 b1 = *(const bf16x8*)(kb + (size_t)(l31 + 32) * HD + doff);
            S0 = MFMA(a_q[ks], b0, S0);
            S1 = MFMA(a_q[ks], b1, S1);
        }

        // ---- G = Q R^T (3 col-tiles; rel B-frags straight from global)
        const int pb = n0 - m0 + 449 + 32 * w;
#pragma unroll
        for (int gt = 0; gt < 3; gt++) {
            f32x16 g;
#pragma unroll
            for (int i = 0; i < 16; i++) g[i] = 0.f;
            int p = pb + 32 * gt + l31;
            p = p < 0 ? 0 : (p > 1024 ? 1024 : p);
            const u16* rb = relb + (size_t)p * HD;
#pragma unroll
            for (int ks = 0; ks < 4; ks++) {
                bf16x8 br = *(const bf16x8*)(rb + 16 * ks + 8 * lh);
                g = MFMA(a_q[ks], br, g);
            }
            int jp = 32 * gt + l31;
#pragma unroll
            for (int rg = 0; rg < 16; rg++) {
                int r = (rg & 3) + 8 * (rg >> 2) + rbase;
                Gw[r * 104 + jp] = f2bf(g[rg]);
            }
        }

        // ---- skew gather (wave-private; per-wave DS ordering + compiler waits)
#pragma unroll
        for (int rg = 0; rg < 16; rg++) {
            int r = (rg & 3) + 8 * (rg >> 2) + rbase;
            int j0 = r - l31 + 63;
            S0[rg] += bf2f(Gw[r * 104 + j0]);
            S1[rg] += bf2f(Gw[r * 104 + j0 - 32]);
        }

        // ---- streaming softmax: raw exp, per-lane partial row-sums
#pragma unroll
        for (int rg = 0; rg < 16; rg++) {
            float e0 = __expf(S0[rg]);
            float e1 = __expf(S1[rg]);
            S0[rg] = e0; S1[rg] = e1;
            li[rg] += e0 + e1;
        }

        // ---- P -> LDS bf16 (swizzled, wave-private)
#pragma unroll
        for (int rg = 0; rg < 16; rg++) {
            int r = (rg & 3) + 8 * (rg >> 2) + rbase;
            int ca = l31, cb = l31 + 32;
            Gw[r * 104 + (((ca >> 3) ^ (r & 7)) * 8) + (ca & 7)] = f2bf(S0[rg]);
            Gw[r * 104 + (((cb >> 3) ^ (r & 7)) * 8) + (cb & 7)] = f2bf(S1[rg]);
        }

        // ---- O += P V  (V B-frags straight from global: 8 contiguous t)
        const u16* vb = v_ws + (size_t)bh * HD * TT + m0;
#pragma unroll
        for (int ms = 0; ms < 4; ms++) {
            const int mg = 2 * ms + lh;
            bf16x8 a_p = *(const bf16x8*)&Gw[l31 * 104 + ((mg ^ (l31 & 7)) * 8)];
            bf16x8 b0 = *(const bf16x8*)(vb + (size_t)l31 * TT + mg * 8);
            bf16x8 b1 = *(const bf16x8*)(vb + (size_t)(l31 + 32) * TT + mg * 8);
            O0 = MFMA(a_p, b0, O0);
            O1 = MFMA(a_p, b1, O1);
        }
    }

    // ---- reduce li partials across the 32 lanes holding each row
#pragma unroll
    for (int rg = 0; rg < 16; rg++) {
        float rs = li[rg];
        rs += __shfl_xor(rs, 1);
        rs += __shfl_xor(rs, 2);
        rs += __shfl_xor(rs, 4);
        rs += __shfl_xor(rs, 8);
        rs += __shfl_xor(rs, 16);
        li[rg] = rs;
    }

    // ---- write bf16 O partials: Opart[s][bh][n][d]; fp32 Lpart[s][bh][n]
    u16* op = Opart + (((size_t)sp * 64 + bh) * TT + n0 + 32 * w) * HD;
#pragma unroll
    for (int rg = 0; rg < 16; rg++) {
        int r = (rg & 3) + 8 * (rg >> 2) + rbase;
        op[(size_t)r * HD + l31]      = f2bf(O0[rg]);
        op[(size_t)r * HD + 32 + l31] = f2bf(O1[rg]);
    }
    if (l31 == 0) {
        float* lp = Lpart + ((size_t)sp * 64 + bh) * TT + n0 + 32 * w;
#pragma unroll
        for (int rg = 0; rg < 16; rg++) {
            int r = (rg & 3) + 8 * (rg >> 2) + rbase;
            lp[r] = li[rg];
        }
    }
}

// ---------------------------------------------------------------------------
// Combine the 2 attention splits: a = (O0+O1)/(l0+l1) -> bf16 [b,t,h*64+d].
// 256 threads = 16 rows x 16 threads (4 d each). Grid: 65536/16 = 4096.
// ---------------------------------------------------------------------------
__global__ __launch_bounds__(256) void attn_combine(
    const u16* __restrict__ Opart, const float* __restrict__ Lpart,
    u16* __restrict__ a_out)
{
    const int tid = threadIdx.x;
    const int row = blockIdx.x * 16 + (tid >> 4);   // 0..65535 over [bh][t]
    const int dq  = (tid & 15) * 4;
    const int bh = row >> 10, n = row & 1023;

    const size_t OS = (size_t)64 * TT * HD;   // split stride (elems)
    size_t o0 = ((size_t)bh * TT + n) * HD + dq;
    ushort4 p0 = *(const ushort4*)(Opart + o0);
    ushort4 p1 = *(const ushort4*)(Opart + OS + o0);
    float l = Lpart[(size_t)bh * TT + n] + Lpart[(size_t)64 * TT + bh * TT + n];
    float inv = 1.0f / l;

    const int b = bh >> 3, h = bh & 7;
    ushort4 o;
    o.x = f2bf((bf2f(p0.x) + bf2f(p1.x)) * inv);
    o.y = f2bf((bf2f(p0.y) + bf2f(p1.y)) * inv);
    o.z = f2bf((bf2f(p0.z) + bf2f(p1.z)) * inv);
    o.w = f2bf((bf2f(p0.w) + bf2f(p1.w)) * inv);
    *(ushort4*)&a_out[((size_t)b * TT + n) * 512 + h * HD + dq] = o;
}

// ---------------------------------------------------------------------------
// Workspace layout (43 MB total — inside the PROVEN 44 MB envelope).
//   [ 0, 8)  q_wsb (B-C)  /  a_wsb (D-E)
//   [ 8,16)  k_wsb
//   [16,24)  v_wsb
//   [24,32)  x_bf (A-B)   /  Opart low half (C-D)
//   [32,40)  Opart high half
//   [40,40.5) Lpart     [40.5,41) relb
//   [41,42.5) WT_all    [42.5,43) WoutT
// ---------------------------------------------------------------------------
extern "C" void kernel_launch(void* const* d_in, const int* in_sizes, int n_in,
                              void* d_out, int out_size, void* d_ws, size_t ws_size,
                              hipStream_t stream)
{
    const float* x    = (const float*)d_in[0];
    const float* Wq   = (const float*)d_in[1];
    const float* bq   = (const float*)d_in[2];
    const float* Wkv  = (const float*)d_in[3];
    const float* bkv  = (const float*)d_in[4];
    const float* Wout = (const float*)d_in[5];
    const float* bout = (const float*)d_in[6];
    const float* rel  = (const float*)d_in[7];
    float* out = (float*)d_out;

    char* ws = (char*)d_ws;
    const size_t MB = 1024 * 1024;
    u16*   q_wsb  = (u16*)(ws);                           // 8 MB [b,h,t,d]
    u16*   a_wsb  = (u16*)(ws);                           // reuse (D-E)
    u16*   k_wsb  = (u16*)(ws + 8 * MB);                  // 8 MB [b,h,t,d]
    u16*   v_wsb  = (u16*)(ws + 16 * MB);                 // 8 MB [b,h,d,t]
    u16*   x_bf   = (u16*)(ws + 24 * MB);                 // 8 MB [8192,512]
    u16*   Opart  = (u16*)(ws + 24 * MB);                 // 16 MB reuse (C-D)
    float* Lpart  = (float*)(ws + 40 * MB);               // 512 KB
    u16*   relb   = (u16*)(ws + 40 * MB + 512 * 1024);    // 128 KB
    u16*   WT_all = (u16*)(ws + 41 * MB);                 // 1.5 MB [1536,512]
    u16*   WoutT  = (u16*)(ws + 42 * MB + 512 * 1024);    // 512 KB [512,512]

    // A: dtype conversions
    cvt_misc<<<(NX4 + NR4 + 255) / 256, 256, 0, stream>>>(x, rel, x_bf, relb);
    cvt_wT<<<256, 256, 0, stream>>>(Wq, Wkv, Wout, WT_all, WT_all + 512 * 512, WoutT);

    // B: fused qkv projection (6144 waves = 24/CU)
    gemm_qkv<<<dim3(64, 24), 256, 0, stream>>>(
        x_bf, WT_all, bq, bkv, q_wsb, k_wsb, v_wsb);

    // C: attention, 2-way K-split, XCD-clustered grid (1024 blocks)
    attn_mfma<<<dim3(64, 16), 256, 0, stream>>>(
        q_wsb, k_wsb, v_wsb, relb, Opart, Lpart);

    // D: combine splits
    attn_combine<<<4096, 256, 0, stream>>>(Opart, Lpart, a_wsb);

    // E: out projection (4096 waves = 16/CU)
    gemm_out<<<dim3(64, 16), 256, 0, stream>>>(a_wsb, WoutT, bout, out);
}